// Round 3
// baseline (81.261 us; speedup 1.0000x reference)
//
#include <hip/hip_runtime.h>
#include <math.h>

constexpr int H = 32, W = 32, C = 128, G = 4, K = 15, K2 = 225, GC = 32;
constexpr int NPIX = H * W;
constexpr int NOFF = G * K2 * 2;   // 1800
constexpr int NMSK = G * K2;       // 900
constexpr int NTOT = NOFF + NMSK;  // 2700
constexpr int KHID = 32;

// workspace layout (float offsets)
constexpr size_t WS_ENV    = 0;        // 225
constexpr size_t WS_KW     = 256;      // 28800 (flat (K2,C) MLP output)
constexpr size_t WS_SCALE  = 29184;    // 128
constexpr size_t WS_PART   = 29312;    // 4096
constexpr size_t WS_XPROJ  = 33792;    // 131072
constexpr size_t WS_XDW    = 164864;   // 131072
constexpr size_t WS_OUTPRE = 295936;   // 131072
constexpr size_t WS_OFFS   = 427008;   // 1843200
constexpr size_t WS_MASK   = 2270208;  // 921600

__device__ __forceinline__ float sigmoidf_(float v) { return 1.f / (1.f + expf(-v)); }
__device__ __forceinline__ float siluf_(float v)    { return v / (1.f + expf(-v)); }

// ---------------- prep: env (block 0) + kernel-MLP kw (4 points/block) ----------------
__device__ __forceinline__ void mlp_point(int k2i, int lane,
                                          const float* __restrict__ k1_w, const float* __restrict__ k1_b,
                                          const float* __restrict__ k2_w, const float* __restrict__ k2_b,
                                          const float* __restrict__ k3_w, const float* __restrict__ k3_b,
                                          float* __restrict__ ws) {
    int i = k2i / 15, j = k2i % 15;
    float ph = (-0.5f + (float)i * (1.f / 14.f)) * 2.f;
    float pw = (-0.5f + (float)j * (1.f / 14.f)) * 2.f;
    float h1[KHID], h2[KHID];
#pragma unroll
    for (int m = 0; m < KHID; m++)
        h1[m] = siluf_(fmaf(ph, k1_w[m], fmaf(pw, k1_w[KHID + m], k1_b[m])));
#pragma unroll
    for (int m = 0; m < KHID; m++) {
        float a = k2_b[m];
#pragma unroll
        for (int q = 0; q < KHID; q++) a = fmaf(h1[q], k2_w[q * KHID + m], a);
        h2[m] = siluf_(a);
    }
#pragma unroll
    for (int t = 0; t < 2; t++) {
        int col = lane + t * 64;
        float a = k3_b[col];
#pragma unroll
        for (int q = 0; q < KHID; q++) a = fmaf(h2[q], k3_w[q * C + col], a);
        ws[WS_KW + (size_t)k2i * C + col] = a;  // kw[g][k][c] = flat[g*7200 + k*32 + c]
    }
}

__global__ __launch_bounds__(256) void prep_kernel(const float* __restrict__ raw_sigma,
                             const float* __restrict__ k1_w, const float* __restrict__ k1_b,
                             const float* __restrict__ k2_w, const float* __restrict__ k2_b,
                             const float* __restrict__ k3_w, const float* __restrict__ k3_b,
                             float* __restrict__ ws) {
    int tid = threadIdx.x;
    if (blockIdx.x == 0) {
        __shared__ float red[256];
        float xs = raw_sigma[0];
        float sp = fmaxf(xs, 0.f) + log1pf(expf(-fabsf(xs)));
        float sigma = fminf(fmaxf(sp, 0.001f), 0.5f);
        float inv2s2 = 1.f / (2.f * sigma * sigma);
        int i = tid / 15, j = tid % 15;
        float e = 0.f;
        if (tid < K2) {
            float gi = -0.5f + (float)i * (1.f / 14.f);
            float gj = -0.5f + (float)j * (1.f / 14.f);
            e = expf(-(gi * gi + gj * gj) * inv2s2);
        }
        red[tid] = e;
        __syncthreads();
        for (int s = 128; s > 0; s >>= 1) {
            if (tid < s) red[tid] += red[tid + s];
            __syncthreads();
        }
        float esum = fmaxf(red[0], 1e-8f);
        if (tid < K2) ws[WS_ENV + tid] = e / esum;
        if (tid < 64) mlp_point(224, tid, k1_w, k1_b, k2_w, k2_b, k3_w, k3_b, ws);
    } else {
        int k2i = (blockIdx.x - 1) * 4 + (tid >> 6);  // 0..223
        mlp_point(k2i, tid & 63, k1_w, k1_b, k2_w, k2_b, k3_w, k3_b, ws);
    }
}

// ---------------- front: x_proj, depthwise conv + silu, pointwise (4 px/block) ----------------
__global__ __launch_bounds__(256) void front_kernel(const float* __restrict__ x,
                             const float* __restrict__ w_in, const float* __restrict__ b_in,
                             const float* __restrict__ dw_k, const float* __restrict__ dw_b,
                             const float* __restrict__ pw_w, const float* __restrict__ pw_b,
                             float* __restrict__ ws) {
    int p0 = blockIdx.x * 4;
    int tid = threadIdx.x;
    int c = tid & 127;
    int pp = tid >> 7;           // pixel pair: handles px pp*2, pp*2+1
    __shared__ float xs[4][C], ts[4][C];
#pragma unroll
    for (int q = 0; q < 2; q++) {
        int px = pp * 2 + q;
        int p = p0 + px;
        int h = p >> 5, w = p & 31;
        xs[px][c] = x[(size_t)p * C + c];
        float y = dw_b[c];
#pragma unroll
        for (int dy = 0; dy < 3; dy++) {
            int hh = h + dy - 1;
            if (hh < 0 || hh >= H) continue;
#pragma unroll
            for (int dx = 0; dx < 3; dx++) {
                int wq = w + dx - 1;
                if (wq < 0 || wq >= W) continue;
                y = fmaf(x[((size_t)hh * W + wq) * C + c], dw_k[(dy * 3 + dx) * C + c], y);
            }
        }
        ts[px][c] = siluf_(y);
    }
    __syncthreads();
    float ap0 = b_in[c], ap1 = b_in[c], ad0 = pw_b[c], ad1 = pw_b[c];
    int b0 = pp * 2, b1 = pp * 2 + 1;
    for (int i = 0; i < C; i += 4) {
#pragma unroll
        for (int u = 0; u < 4; u++) {
            float wi = w_in[(size_t)(i + u) * C + c];
            float pi = pw_w[(size_t)(i + u) * C + c];
            ap0 = fmaf(xs[b0][i + u], wi, ap0);
            ap1 = fmaf(xs[b1][i + u], wi, ap1);
            ad0 = fmaf(ts[b0][i + u], pi, ad0);
            ad1 = fmaf(ts[b1][i + u], pi, ad1);
        }
    }
    ws[WS_XPROJ + (size_t)(p0 + b0) * C + c] = ap0;
    ws[WS_XPROJ + (size_t)(p0 + b1) * C + c] = ap1;
    ws[WS_XDW  + (size_t)(p0 + b0) * C + c] = ad0;
    ws[WS_XDW  + (size_t)(p0 + b1) * C + c] = ad1;
}

// ---------------- combined offs+mask GEMM: tile 64(M) x 64(N), 4x4 per thread ----------------
__global__ __launch_bounds__(256) void offmsk_gemm(const float* __restrict__ A,
                                                   const float* __restrict__ off_w,
                                                   const float* __restrict__ off_b,
                                                   const float* __restrict__ msk_w,
                                                   const float* __restrict__ msk_b,
                                                   const float* __restrict__ bos,
                                                   const float* __restrict__ env,
                                                   float* __restrict__ offs_out,
                                                   float* __restrict__ mask_out) {
    __shared__ float At[32][72];   // transposed A tile (k-major), stride 72
    __shared__ float Bs[32][64];
    int tid = threadIdx.x;
    int c0 = blockIdx.x * 64;
    int p0 = blockIdx.y * 64;
    int tx = tid & 15, ty = tid >> 4;

    float acc[4][4];
#pragma unroll
    for (int i = 0; i < 4; i++)
#pragma unroll
        for (int j = 0; j < 4; j++) acc[i][j] = 0.f;

    int cL = (tid * 4) & 63;
    int kL = (tid * 4) >> 6;       // 0..15; pass adds 16
    int cB = c0 + cL;
    const float* bptr = nullptr; int bstride = 0;
    if (cB < NOFF)       { bptr = off_w + cB;          bstride = NOFF; }
    else if (cB < NTOT)  { bptr = msk_w + (cB - NOFF); bstride = NMSK; }
    int rA = tid >> 3, k4A = (tid & 7) * 4;

    for (int kt = 0; kt < C; kt += 32) {
        if (kt) __syncthreads();
#pragma unroll
        for (int pass = 0; pass < 2; pass++) {
            int r = rA + pass * 32;
            float4 v = *(const float4*)&A[(size_t)(p0 + r) * C + kt + k4A];
            At[k4A + 0][r] = v.x; At[k4A + 1][r] = v.y;
            At[k4A + 2][r] = v.z; At[k4A + 3][r] = v.w;
            int k = kL + pass * 16;
            float4 bv = make_float4(0.f, 0.f, 0.f, 0.f);
            if (bptr) bv = *(const float4*)&bptr[(size_t)(kt + k) * bstride];
            *(float4*)&Bs[k][cL] = bv;
        }
        __syncthreads();
#pragma unroll
        for (int k = 0; k < 32; k++) {
            float4 a4 = *(const float4*)&At[k][ty * 4];
            float4 b4 = *(const float4*)&Bs[k][tx * 4];
            const float av[4] = {a4.x, a4.y, a4.z, a4.w};
            const float bv[4] = {b4.x, b4.y, b4.z, b4.w};
#pragma unroll
            for (int i = 0; i < 4; i++)
#pragma unroll
                for (int j = 0; j < 4; j++)
                    acc[i][j] = fmaf(av[i], bv[j], acc[i][j]);
        }
    }

    int colbase = c0 + tx * 4;
    if (colbase >= NTOT) return;
    float bias[4], sc[4];
    float* obase;
    int ostride;
    if (colbase < NOFF) {
        float s = bos[0];
#pragma unroll
        for (int j = 0; j < 4; j++) { bias[j] = off_b[colbase + j]; sc[j] = s; }
        obase = offs_out + colbase; ostride = NOFF;
    } else {
        int m0 = colbase - NOFF;
#pragma unroll
        for (int j = 0; j < 4; j++) { bias[j] = msk_b[m0 + j]; sc[j] = env[(m0 + j) % K2]; }
        obase = mask_out + m0; ostride = NMSK;
    }
#pragma unroll
    for (int i = 0; i < 4; i++) {
        size_t row = (size_t)(p0 + ty * 4 + i);
        float4 r0 = make_float4((acc[i][0] + bias[0]) * sc[0], (acc[i][1] + bias[1]) * sc[1],
                                (acc[i][2] + bias[2]) * sc[2], (acc[i][3] + bias[3]) * sc[3]);
        *(float4*)&obase[row * ostride] = r0;
    }
}

// ---------------- sampler: softmax + bilinear deformable sampling (2 px/block) ----------------
__global__ __launch_bounds__(256) void sampler_kernel(const float* __restrict__ ws_offs,
                                                      const float* __restrict__ ws_mask,
                                                      const float* __restrict__ xproj,
                                                      const float* __restrict__ kwf,
                                                      float* __restrict__ outpre) {
    int p0 = blockIdx.x * 2;
    int h = p0 >> 5;               // both pixels same row
    int tid = threadIdx.x;

    __shared__ float   attn_s[2][NMSK];   // 7.2 KB
    __shared__ float4  wgt_s[2][NMSK];    // 28.8 KB
    __shared__ ushort4 loc_s[2][NMSK];    // 14.4 KB

    // phase 1: softmax over K2 per (px,g): 8 combos on 8 half-waves
    {
        int half = tid >> 5;       // 0..7
        int l32 = tid & 31;
        int px = half >> 2, g = half & 3;
        const float* mrow = ws_mask + (size_t)(p0 + px) * NMSK + g * K2;
        float v[8];
        float mx = -1e30f;
#pragma unroll
        for (int q = 0; q < 8; q++) {
            int k = l32 + q * 32;
            v[q] = (k < K2) ? mrow[k] : -1e30f;
            mx = fmaxf(mx, v[q]);
        }
#pragma unroll
        for (int s = 16; s > 0; s >>= 1) mx = fmaxf(mx, __shfl_xor(mx, s));
        float sum = 0.f;
#pragma unroll
        for (int q = 0; q < 8; q++) {
            int k = l32 + q * 32;
            v[q] = (k < K2) ? expf(v[q] - mx) : 0.f;
            sum += v[q];
        }
#pragma unroll
        for (int s = 16; s > 0; s >>= 1) sum += __shfl_xor(sum, s);
        float inv = 1.f / sum;
#pragma unroll
        for (int q = 0; q < 8; q++) {
            int k = l32 + q * 32;
            if (k < K2) attn_s[px][g * K2 + k] = v[q] * inv;
        }
    }
    __syncthreads();

    // phase 2: bilinear weights (attn*valid folded) + packed corner indices
    for (int e = tid; e < 2 * NMSK; e += 256) {
        int px = (e >= NMSK) ? 1 : 0;
        int m = e - px * NMSK;
        int g = m / K2;
        int k = m - g * K2;
        int p = p0 + px;
        int w = p & 31;
        float2 o = *(const float2*)&ws_offs[(size_t)p * NOFF + m * 2];
        float abs_h = (float)(h + k / 15 - 7) + o.x;
        float abs_w = (float)(w + k % 15 - 7) + o.y;
        float validf = (abs_h < 0.f || abs_h > 31.f || abs_w < 0.f || abs_w > 31.f) ? 0.f : 1.f;
        float ah = fminf(fmaxf(abs_h, 0.f), 31.f);
        float aw = fminf(fmaxf(abs_w, 0.f), 31.f);
        int hf = (int)ah, wf = (int)aw;
        int hc = min(hf + 1, 31), wc = min(wf + 1, 31);
        float hwt = ah - (float)hf, wwt = aw - (float)wf;
        float a = attn_s[px][m] * validf;
        float u0 = 1.f - hwt, u1 = 1.f - wwt;
        wgt_s[px][m] = make_float4(a * u0 * u1, a * u0 * wwt, a * hwt * u1, a * hwt * wwt);
        loc_s[px][m] = make_ushort4((unsigned short)(hf * W + wf), (unsigned short)(hf * W + wc),
                                    (unsigned short)(hc * W + wf), (unsigned short)(hc * W + wc));
    }
    __syncthreads();

    // phase 3: px(2) x g(4) x s(4) x cq(8); shuffle-reduce over s
    {
        int cq = tid & 7;
        int s  = (tid >> 3) & 3;
        int g  = (tid >> 5) & 3;
        int px = tid >> 7;
        int k0 = (s * K2) >> 2;
        int k1 = ((s + 1) * K2) >> 2;
        const float* xpg = xproj + g * GC + cq * 4;
        const float* kwg = kwf + (size_t)g * (K2 * GC) + cq * 4;
        float4 acc = make_float4(0.f, 0.f, 0.f, 0.f);
        for (int k = k0; k < k1; k++) {
            int m = g * K2 + k;
            ushort4 L  = loc_s[px][m];
            float4  Wv = wgt_s[px][m];
            float4 x00 = *(const float4*)(xpg + (int)L.x * C);
            float4 x01 = *(const float4*)(xpg + (int)L.y * C);
            float4 x10 = *(const float4*)(xpg + (int)L.z * C);
            float4 x11 = *(const float4*)(xpg + (int)L.w * C);
            float4 kw4 = *(const float4*)(kwg + k * GC);
            float sx = fmaf(Wv.w, x11.x, fmaf(Wv.z, x10.x, fmaf(Wv.y, x01.x, Wv.x * x00.x)));
            float sy = fmaf(Wv.w, x11.y, fmaf(Wv.z, x10.y, fmaf(Wv.y, x01.y, Wv.x * x00.y)));
            float sz = fmaf(Wv.w, x11.z, fmaf(Wv.z, x10.z, fmaf(Wv.y, x01.z, Wv.x * x00.z)));
            float sw = fmaf(Wv.w, x11.w, fmaf(Wv.z, x10.w, fmaf(Wv.y, x01.w, Wv.x * x00.w)));
            acc.x = fmaf(kw4.x, sx, acc.x);
            acc.y = fmaf(kw4.y, sy, acc.y);
            acc.z = fmaf(kw4.z, sz, acc.z);
            acc.w = fmaf(kw4.w, sw, acc.w);
        }
        // reduce over s: lanes differing in tid bits 3,4 (same wave)
        acc.x += __shfl_xor(acc.x, 8);  acc.y += __shfl_xor(acc.y, 8);
        acc.z += __shfl_xor(acc.z, 8);  acc.w += __shfl_xor(acc.w, 8);
        acc.x += __shfl_xor(acc.x, 16); acc.y += __shfl_xor(acc.y, 16);
        acc.z += __shfl_xor(acc.z, 16); acc.w += __shfl_xor(acc.w, 16);
        if (s == 0)
            *(float4*)&outpre[(size_t)(p0 + px) * C + g * GC + cq * 4] = acc;
    }
}

// ---------------- pooled mean + SE MLP ----------------
__global__ void reduce1_kernel(const float* __restrict__ outpre, float* __restrict__ part) {
    int b = blockIdx.x;
    int c = threadIdx.x;
    float s = 0.f;
    for (int q = 0; q < 32; q++) s += outpre[(size_t)(b * 32 + q) * C + c];
    part[(size_t)b * C + c] = s;
}

__global__ void se_kernel(const float* __restrict__ part,
                          const float* __restrict__ se1_w, const float* __restrict__ se1_b,
                          const float* __restrict__ se2_w, const float* __restrict__ se2_b,
                          float* __restrict__ scale_out) {
    __shared__ float pooled[C];
    __shared__ float hid[KHID];
    int tid = threadIdx.x;
    float s = 0.f;
    for (int b = 0; b < 32; b++) s += part[(size_t)b * C + tid];
    pooled[tid] = s * (1.f / 1024.f);
    __syncthreads();
    if (tid < KHID) {
        float a = se1_b[tid];
        for (int cc = 0; cc < C; cc++) a = fmaf(pooled[cc], se1_w[cc * KHID + tid], a);
        hid[tid] = siluf_(a);
    }
    __syncthreads();
    float a = se2_b[tid];
#pragma unroll
    for (int q = 0; q < KHID; q++) a = fmaf(hid[q], se2_w[q * C + tid], a);
    scale_out[tid] = sigmoidf_(a);
}

// ---------------- final: out = (out_pre * scale) @ w_out + b_out (4 px/block) ----------------
__global__ __launch_bounds__(256) void final_kernel(const float* __restrict__ outpre,
                             const float* __restrict__ scale,
                             const float* __restrict__ w_out, const float* __restrict__ b_out,
                             float* __restrict__ out) {
    int p0 = blockIdx.x * 4;
    int tid = threadIdx.x;
    int c = tid & 127;
    int pp = tid >> 7;
    __shared__ float v[4][C];
    float scv = scale[c];
#pragma unroll
    for (int q = 0; q < 2; q++) {
        int px = pp * 2 + q;
        v[px][c] = outpre[(size_t)(p0 + px) * C + c] * scv;
    }
    __syncthreads();
    float a0 = b_out[c], a1 = b_out[c];
    int b0 = pp * 2, b1 = pp * 2 + 1;
    for (int i = 0; i < C; i += 4) {
#pragma unroll
        for (int u = 0; u < 4; u++) {
            float wv = w_out[(size_t)(i + u) * C + c];
            a0 = fmaf(v[b0][i + u], wv, a0);
            a1 = fmaf(v[b1][i + u], wv, a1);
        }
    }
    out[(size_t)(p0 + b0) * C + c] = a0;
    out[(size_t)(p0 + b1) * C + c] = a1;
}

extern "C" void kernel_launch(void* const* d_in, const int* in_sizes, int n_in,
                              void* d_out, int out_size, void* d_ws, size_t ws_size,
                              hipStream_t stream) {
    const float* x         = (const float*)d_in[0];
    const float* raw_sigma = (const float*)d_in[1];
    const float* bos       = (const float*)d_in[2];
    const float* w_in      = (const float*)d_in[3];
    const float* b_in      = (const float*)d_in[4];
    const float* w_out     = (const float*)d_in[5];
    const float* b_out     = (const float*)d_in[6];
    const float* dw_k      = (const float*)d_in[7];
    const float* dw_b      = (const float*)d_in[8];
    const float* pw_w      = (const float*)d_in[9];
    const float* pw_b      = (const float*)d_in[10];
    const float* off_w     = (const float*)d_in[11];
    const float* off_b     = (const float*)d_in[12];
    const float* msk_w     = (const float*)d_in[13];
    const float* msk_b     = (const float*)d_in[14];
    const float* k1_w      = (const float*)d_in[15];
    const float* k1_b      = (const float*)d_in[16];
    const float* k2_w      = (const float*)d_in[17];
    const float* k2_b      = (const float*)d_in[18];
    const float* k3_w      = (const float*)d_in[19];
    const float* k3_b      = (const float*)d_in[20];
    const float* se1_w     = (const float*)d_in[21];
    const float* se1_b     = (const float*)d_in[22];
    const float* se2_w     = (const float*)d_in[23];
    const float* se2_b     = (const float*)d_in[24];

    float* ws  = (float*)d_ws;
    float* out = (float*)d_out;

    prep_kernel<<<57, 256, 0, stream>>>(raw_sigma, k1_w, k1_b, k2_w, k2_b, k3_w, k3_b, ws);
    front_kernel<<<NPIX / 4, 256, 0, stream>>>(x, w_in, b_in, dw_k, dw_b, pw_w, pw_b, ws);

    dim3 gg((NTOT + 63) / 64, NPIX / 64);
    offmsk_gemm<<<gg, 256, 0, stream>>>(ws + WS_XDW, off_w, off_b, msk_w, msk_b, bos,
                                        ws + WS_ENV, ws + WS_OFFS, ws + WS_MASK);

    sampler_kernel<<<NPIX / 2, 256, 0, stream>>>(ws + WS_OFFS, ws + WS_MASK, ws + WS_XPROJ,
                                                 ws + WS_KW, ws + WS_OUTPRE);

    reduce1_kernel<<<32, C, 0, stream>>>(ws + WS_OUTPRE, ws + WS_PART);
    se_kernel<<<1, C, 0, stream>>>(ws + WS_PART, se1_w, se1_b, se2_w, se2_b, ws + WS_SCALE);
    final_kernel<<<NPIX / 4, 256, 0, stream>>>(ws + WS_OUTPRE, ws + WS_SCALE, w_out, b_out, out);
}